// Round 4
// baseline (623.383 us; speedup 1.0000x reference)
//
#include <hip/hip_runtime.h>
#include <hip/hip_bf16.h>

#define NB 32768
#define DIN 512
#define DHID 4096
#define DOUT 512

typedef __attribute__((ext_vector_type(8))) __bf16 bf16x8;
typedef __attribute__((ext_vector_type(4))) float f32x4;
typedef __attribute__((ext_vector_type(16))) float f32x16;

__device__ __forceinline__ unsigned short f2bf(float f) {
  unsigned u = __builtin_bit_cast(unsigned, f);
  u += 0x7FFFu + ((u >> 16) & 1u);
  return (unsigned short)(u >> 16);
}

__device__ __forceinline__ void gload16(void* lds, const void* g) {
  __builtin_amdgcn_global_load_lds(
      (const __attribute__((address_space(1))) void*)g,
      (__attribute__((address_space(3))) void*)lds, 16, 0, 0);
}

// ---------------- prep: xn = bf16((x - mean)/std) ----------------
__global__ __launch_bounds__(256) void k_prep_x(
    const float4* __restrict__ x, const float* __restrict__ mean,
    const float* __restrict__ stdv, ushort4* __restrict__ xn) {
  const int i = blockIdx.x * 256 + threadIdx.x;
  const int col = (i << 2) & (DIN - 1);
  const float4 v = x[i];
  const float4 m = *(const float4*)(mean + col);
  const float4 s = *(const float4*)(stdv + col);
  ushort4 o;
  o.x = f2bf((v.x - m.x) / s.x);
  o.y = f2bf((v.y - m.y) / s.y);
  o.z = f2bf((v.z - m.z) / s.z);
  o.w = f2bf((v.w - m.w) / s.w);
  xn[i] = o;
}

// ---------------- generic f32 -> bf16 convert ----------------
__global__ __launch_bounds__(256) void k_cvt(
    const float4* __restrict__ in, ushort4* __restrict__ out) {
  const int i = blockIdx.x * 256 + threadIdx.x;
  const float4 v = in[i];
  ushort4 o;
  o.x = f2bf(v.x); o.y = f2bf(v.y); o.z = f2bf(v.z); o.w = f2bf(v.w);
  out[i] = o;
}

// ---------------- NT GEMM: out[m][n] = sum_k A[m][k]*W[n][k] + bias[n]
// Block tile 256(M) x 256(N) x 64(K), 512 threads = 8 waves (2M x 4N),
// wave tile 128x64 via 4x2 frags of mfma_f32_32x32x16_bf16.
// LDS plane-major: [kc(8)][256 rows][16B] per operand (32 KB A + 32 KB B),
// 2-slot double buffer (128 KB). 32-row fragment reads are stride-16B dense
// -> conflict-free, no swizzle. STAGE(t+1) issued before compute(t); one
// vmcnt(0)+s_barrier per K-tile (loads land under ~2000 cy of MFMA).
// EPI==0: relu + bf16 store (h).  EPI==1: f32 store (res).
template <int EPI>
__global__ __launch_bounds__(512, 1) void k_gemm(
    const unsigned short* __restrict__ A, const unsigned short* __restrict__ W,
    const float* __restrict__ bias, void* __restrict__ outp,
    const int N, const int K, const int nbn) {
  __shared__ __align__(16) char lds[2 * 65536];
  const int tid = threadIdx.x;
  const int wave = tid >> 6, lane = tid & 63;
  const int wm = wave >> 2, wn = wave & 3;  // 2(M) x 4(N) wave grid
  const int l31 = lane & 31, lhi = lane >> 5;

  // XCD-aware bijective swizzle (m204), valid for any nwg
  const int nwg = (int)gridDim.x;
  const int wg = (int)blockIdx.x;
  const int q = nwg >> 3, r = nwg & 7;
  const int xcd = wg & 7, loc = wg >> 3;
  const int swz = (xcd < r ? xcd * (q + 1) : r * (q + 1) + (xcd - r) * q) + loc;
  const int bm = swz / nbn, bn = swz % nbn;
  const int R0 = bm * 256, C0 = bn * 256;

  const int NT = K >> 6;

  // Stage tile t into slot s. LDS linear dest (per-lane +16B), global src
  // pre-scattered to match plane-major layout: chunk c -> plane kc=c>>2,
  // rows (c&3)*64 + lane.
  auto STAGE = [&](int t, int s) {
    char* as = lds + s * 65536;
    char* bs = as + 32768;
    const int k0 = t << 6;
#pragma unroll
    for (int i = 0; i < 4; ++i) {
      const int c = wave * 4 + i;  // 0..31
      const int kc = c >> 2;
      const int row = ((c & 3) << 6) + lane;
      gload16(as + c * 1024,
              (const void*)(A + (size_t)(R0 + row) * K + k0 + kc * 8));
    }
#pragma unroll
    for (int i = 0; i < 4; ++i) {
      const int c = wave * 4 + i;
      const int kc = c >> 2;
      const int row = ((c & 3) << 6) + lane;
      gload16(bs + c * 1024,
              (const void*)(W + (size_t)(C0 + row) * K + k0 + kc * 8));
    }
  };

  f32x16 acc[4][2] = {};

  STAGE(0, 0);
  asm volatile("s_waitcnt vmcnt(0)" ::: "memory");
  __builtin_amdgcn_s_barrier();

  for (int t = 0; t < NT; ++t) {
    const int s = t & 1;
    if (t + 1 < NT) STAGE(t + 1, s ^ 1);
    const char* as = lds + s * 65536;
    const char* bs = as + 32768;
#pragma unroll
    for (int ks = 0; ks < 4; ++ks) {
      const int kc = ks * 2 + lhi;  // this lane's k-plane
      bf16x8 af[4], bw[2];
#pragma unroll
      for (int mi = 0; mi < 4; ++mi)
        af[mi] = *(const bf16x8*)(as + kc * 4096 +
                                  (wm * 128 + mi * 32 + l31) * 16);
#pragma unroll
      for (int nj = 0; nj < 2; ++nj)
        bw[nj] = *(const bf16x8*)(bs + kc * 4096 +
                                  (wn * 64 + nj * 32 + l31) * 16);
      __builtin_amdgcn_s_setprio(1);
#pragma unroll
      for (int mi = 0; mi < 4; ++mi)
#pragma unroll
        for (int nj = 0; nj < 2; ++nj)
          acc[mi][nj] = __builtin_amdgcn_mfma_f32_32x32x16_bf16(
              af[mi], bw[nj], acc[mi][nj], 0, 0, 0);
      __builtin_amdgcn_s_setprio(0);
    }
    asm volatile("s_waitcnt vmcnt(0)" ::: "memory");
    __builtin_amdgcn_s_barrier();
  }

  // epilogue: 32x32 C/D map (m74/m101): col=lane&31, row=(reg&3)+8*(reg>>2)+4*lhi
  const int m_base = R0 + wm * 128;
  const int n_base = C0 + wn * 64 + l31;
#pragma unroll
  for (int nj = 0; nj < 2; ++nj) {
    const int n = n_base + nj * 32;
    const float bv = bias[n];
#pragma unroll
    for (int mi = 0; mi < 4; ++mi) {
#pragma unroll
      for (int reg = 0; reg < 16; ++reg) {
        const int row = (reg & 3) + 8 * (reg >> 2) + 4 * lhi;
        const int m = m_base + mi * 32 + row;
        float v = acc[mi][nj][reg] + bv;
        if (EPI == 0) {
          v = fmaxf(v, 0.0f);
          ((unsigned short*)outp)[(size_t)m * N + n] = f2bf(v);
        } else {
          ((float*)outp)[(size_t)m * N + n] = v;
        }
      }
    }
  }
}

// ---------------- finalize (in-place on res==out): clip, affine, +x, row-normalize ----------------
__global__ __launch_bounds__(256) void k_finalize(
    float* __restrict__ res, const float* __restrict__ x,
    const float* __restrict__ out_mean, const float* __restrict__ out_std,
    const float* __restrict__ in_mean, const int* __restrict__ nmp) {
  const int wave = threadIdx.x >> 6, lane = threadIdx.x & 63;
  const size_t row = (size_t)blockIdx.x * 4 + wave;
  const float nm = (float)(*nmp);
  const size_t base = row * DOUT + (size_t)lane * 8;
  const int c = lane * 8;
  const float4 r0 = *(const float4*)(res + base);
  const float4 r1 = *(const float4*)(res + base + 4);
  float ss = r0.x * r0.x + r0.y * r0.y + r0.z * r0.z + r0.w * r0.w +
             r1.x * r1.x + r1.y * r1.y + r1.z * r1.z + r1.w * r1.w;
#pragma unroll
  for (int o = 32; o > 0; o >>= 1) ss += __shfl_xor(ss, o);
  const float rn = sqrtf(ss);
  const float sc = (rn > nm) ? (nm / rn) : 1.0f;
  const float4 os0 = *(const float4*)(out_std + c);
  const float4 os1 = *(const float4*)(out_std + c + 4);
  const float4 om0 = *(const float4*)(out_mean + c);
  const float4 om1 = *(const float4*)(out_mean + c + 4);
  const float4 im0 = *(const float4*)(in_mean + c);
  const float4 im1 = *(const float4*)(in_mean + c + 4);
  const float4 x0 = *(const float4*)(x + base);
  const float4 x1 = *(const float4*)(x + base + 4);
  float4 m0, m1;
  m0.x = r0.x * sc * os0.x + om0.x - im0.x + x0.x;
  m0.y = r0.y * sc * os0.y + om0.y - im0.y + x0.y;
  m0.z = r0.z * sc * os0.z + om0.z - im0.z + x0.z;
  m0.w = r0.w * sc * os0.w + om0.w - im0.w + x0.w;
  m1.x = r1.x * sc * os1.x + om1.x - im1.x + x1.x;
  m1.y = r1.y * sc * os1.y + om1.y - im1.y + x1.y;
  m1.z = r1.z * sc * os1.z + om1.z - im1.z + x1.z;
  m1.w = r1.w * sc * os1.w + om1.w - im1.w + x1.w;
  float s2 = m0.x * m0.x + m0.y * m0.y + m0.z * m0.z + m0.w * m0.w +
             m1.x * m1.x + m1.y * m1.y + m1.z * m1.z + m1.w * m1.w;
#pragma unroll
  for (int o = 32; o > 0; o >>= 1) s2 += __shfl_xor(s2, o);
  const float inv = 1.0f / fmaxf(sqrtf(s2), 1e-12f);
  float4 o0, o1;
  o0.x = m0.x * inv; o0.y = m0.y * inv; o0.z = m0.z * inv; o0.w = m0.w * inv;
  o1.x = m1.x * inv; o1.y = m1.y * inv; o1.z = m1.z * inv; o1.w = m1.w * inv;
  *(float4*)(res + base) = o0;
  *(float4*)(res + base + 4) = o1;
}

extern "C" void kernel_launch(void* const* d_in, const int* in_sizes, int n_in,
                              void* d_out, int out_size, void* d_ws, size_t ws_size,
                              hipStream_t stream) {
  const float* x = (const float*)d_in[0];
  const float* in_mean = (const float*)d_in[1];
  const float* in_std = (const float*)d_in[2];
  const float* out_mean = (const float*)d_in[3];
  const float* out_std = (const float*)d_in[4];
  const float* W1 = (const float*)d_in[5];
  const float* b1 = (const float*)d_in[6];
  const float* W2 = (const float*)d_in[7];
  const float* b2 = (const float*)d_in[8];
  const int* nmp = (const int*)d_in[9];
  float* out = (float*)d_out;

  // ---- workspace layout (adaptive: h holds only `chunk` batch rows) ----
  char* ws = (char*)d_ws;
  unsigned short* xn = (unsigned short*)ws;   ws += (size_t)NB * DIN * 2;    // 32 MB
  unsigned short* W1b = (unsigned short*)ws;  ws += (size_t)DHID * DIN * 2;  //  4 MB
  unsigned short* W2b = (unsigned short*)ws;  ws += (size_t)DOUT * DHID * 2; //  4 MB
  unsigned short* h = (unsigned short*)ws;    // chunk * DHID bf16

  const size_t fixedB = (size_t)(ws - (char*)d_ws);
  const size_t avail = (ws_size > fixedB) ? (ws_size - fixedB) : 0;
  long long crows = (long long)(avail / ((size_t)DHID * 2));
  if (crows > NB) crows = NB;
  crows &= ~255LL;                 // multiple of 256 (BM)
  if (crows < 256) crows = 256;
  const int chunk = (int)crows;

  // 1) xn = bf16((x - in_mean)/in_std)
  k_prep_x<<<16384, 256, 0, stream>>>((const float4*)x, in_mean, in_std,
                                      (ushort4*)xn);
  // 2) W1, W2 -> bf16
  k_cvt<<<2048, 256, 0, stream>>>((const float4*)W1, (ushort4*)W1b);
  k_cvt<<<2048, 256, 0, stream>>>((const float4*)W2, (ushort4*)W2b);

  // 3) per-chunk: h = relu(xn@W1^T + b1); res(=d_out) = h@W2^T + b2
  for (int s = 0; s < NB; s += chunk) {
    const int mc = (NB - s < chunk) ? (NB - s) : chunk;
    const int g1 = (mc / 256) * (DHID / 256);
    k_gemm<0><<<g1, 512, 0, stream>>>(xn + (size_t)s * DIN, W1b, b1, (void*)h,
                                      DHID, DIN, DHID / 256);
    const int g2 = (mc / 256) * (DOUT / 256);
    k_gemm<1><<<g2, 512, 0, stream>>>(h, W2b, b2, (void*)(out + (size_t)s * DOUT),
                                      DOUT, DHID, DOUT / 256);
  }

  // 4) finalize in-place on d_out
  k_finalize<<<NB / 4, 256, 0, stream>>>(out, x, out_mean, out_std, in_mean, nmp);
}

// Round 5
// 616.127 us; speedup vs baseline: 1.0118x; 1.0118x over previous
//
#include <hip/hip_runtime.h>
#include <hip/hip_bf16.h>

#define NB 32768
#define DIN 512
#define DHID 4096
#define DOUT 512

typedef __attribute__((ext_vector_type(8))) __bf16 bf16x8;
typedef __attribute__((ext_vector_type(4))) float f32x4;
typedef __attribute__((ext_vector_type(16))) float f32x16;

__device__ __forceinline__ unsigned short f2bf(float f) {
  unsigned u = __builtin_bit_cast(unsigned, f);
  u += 0x7FFFu + ((u >> 16) & 1u);
  return (unsigned short)(u >> 16);
}

__device__ __forceinline__ void gload16(void* lds, const void* g) {
  __builtin_amdgcn_global_load_lds(
      (const __attribute__((address_space(1))) void*)g,
      (__attribute__((address_space(3))) void*)lds, 16, 0, 0);
}

// ---------------- prep: xn = bf16((x - mean)/std) ----------------
__global__ __launch_bounds__(256) void k_prep_x(
    const float4* __restrict__ x, const float* __restrict__ mean,
    const float* __restrict__ stdv, ushort4* __restrict__ xn) {
  const int i = blockIdx.x * 256 + threadIdx.x;
  const int col = (i << 2) & (DIN - 1);
  const float4 v = x[i];
  const float4 m = *(const float4*)(mean + col);
  const float4 s = *(const float4*)(stdv + col);
  ushort4 o;
  o.x = f2bf((v.x - m.x) / s.x);
  o.y = f2bf((v.y - m.y) / s.y);
  o.z = f2bf((v.z - m.z) / s.z);
  o.w = f2bf((v.w - m.w) / s.w);
  xn[i] = o;
}

// ---------------- generic f32 -> bf16 convert ----------------
__global__ __launch_bounds__(256) void k_cvt(
    const float4* __restrict__ in, ushort4* __restrict__ out) {
  const int i = blockIdx.x * 256 + threadIdx.x;
  const float4 v = in[i];
  ushort4 o;
  o.x = f2bf(v.x); o.y = f2bf(v.y); o.z = f2bf(v.z); o.w = f2bf(v.w);
  out[i] = o;
}

// ---------------- NT GEMM: out[m][n] = sum_k A[m][k]*W[n][k] + bias[n]
// Block tile 256(M) x 256(N) x 32(K), 512 threads = 8 waves (2M x 4N),
// wave tile 128x64 via 4x2 frags of mfma_f32_32x32x16_bf16.
// LDS: 4-slot ring, 32 KB/slot (A 16K + B 16K), plane-major
// [kc(4)][256 rows][16B] -> stride-16B dense fragment reads, conflict-free.
// Pipeline: stage t+3 while computing t; counted s_waitcnt vmcnt(8) keeps
// stages t+2,t+3 in flight across the barrier (never drain mid-loop).
// EPI==0: relu + bf16 store (h).  EPI==1: f32 store (res).
template <int EPI>
__global__ __launch_bounds__(512, 1) void k_gemm(
    const unsigned short* __restrict__ A, const unsigned short* __restrict__ W,
    const float* __restrict__ bias, void* __restrict__ outp,
    const int N, const int K, const int nbn) {
  __shared__ __align__(16) char lds[4 * 32768];
  const int tid = threadIdx.x;
  const int wave = tid >> 6, lane = tid & 63;
  const int wm = wave >> 2, wn = wave & 3;  // 2(M) x 4(N) wave grid
  const int l31 = lane & 31, lhi = lane >> 5;

  // XCD-aware bijective swizzle (m204), valid for any nwg
  const int nwg = (int)gridDim.x;
  const int wg = (int)blockIdx.x;
  const int q = nwg >> 3, r = nwg & 7;
  const int xcd = wg & 7, loc = wg >> 3;
  const int swz = (xcd < r ? xcd * (q + 1) : r * (q + 1) + (xcd - r) * q) + loc;
  const int bm = swz / nbn, bn = swz % nbn;
  const int R0 = bm * 256, C0 = bn * 256;

  const int NT = K >> 5;  // BK = 32

  // Stage tile t into slot s: 16 A-chunks + 16 B-chunks of 1 KB, 4/wave.
  // Chunk c: plane kc = c>>2 (k-offset kc*8), rows (c&3)*64 + lane.
  // LDS dest linear (lane*16 auto); global src pre-scattered to plane-major.
  auto STAGE = [&](int t, int s) {
    char* as = lds + s * 32768;
    char* bs = as + 16384;
    const int k0 = t << 5;
#pragma unroll
    for (int i = 0; i < 2; ++i) {
      const int c = wave * 2 + i;  // 0..15
      const int kc = c >> 2;
      const int row = ((c & 3) << 6) + lane;
      gload16(as + c * 1024,
              (const void*)(A + (size_t)(R0 + row) * K + k0 + kc * 8));
    }
#pragma unroll
    for (int i = 0; i < 2; ++i) {
      const int c = wave * 2 + i;
      const int kc = c >> 2;
      const int row = ((c & 3) << 6) + lane;
      gload16(bs + c * 1024,
              (const void*)(W + (size_t)(C0 + row) * K + k0 + kc * 8));
    }
  };

  f32x16 acc[4][2] = {};

  STAGE(0, 0);
  STAGE(1, 1);
  STAGE(2, 2);
  asm volatile("s_waitcnt vmcnt(8)" ::: "memory");  // tile 0 landed
  __builtin_amdgcn_s_barrier();

  for (int t = 0; t < NT; ++t) {
    if (t + 3 < NT) STAGE(t + 3, (t + 3) & 3);
    const char* as = lds + (t & 3) * 32768;
    const char* bs = as + 16384;
#pragma unroll
    for (int ks = 0; ks < 2; ++ks) {
      const int kc = ks * 2 + lhi;  // this lane's k-plane
      bf16x8 af[4], bw[2];
#pragma unroll
      for (int mi = 0; mi < 4; ++mi)
        af[mi] = *(const bf16x8*)(as + kc * 4096 +
                                  (wm * 128 + mi * 32 + l31) * 16);
#pragma unroll
      for (int nj = 0; nj < 2; ++nj)
        bw[nj] = *(const bf16x8*)(bs + kc * 4096 +
                                  (wn * 64 + nj * 32 + l31) * 16);
      __builtin_amdgcn_s_setprio(1);
#pragma unroll
      for (int mi = 0; mi < 4; ++mi)
#pragma unroll
        for (int nj = 0; nj < 2; ++nj)
          acc[mi][nj] = __builtin_amdgcn_mfma_f32_32x32x16_bf16(
              af[mi], bw[nj], acc[mi][nj], 0, 0, 0);
      __builtin_amdgcn_s_setprio(0);
    }
    // leave stages for t+2,t+3 in flight; ensure t+1 landed
    if (t + 3 < NT) {
      asm volatile("s_waitcnt vmcnt(8)" ::: "memory");
    } else if (t + 2 < NT) {
      asm volatile("s_waitcnt vmcnt(4)" ::: "memory");
    } else {
      asm volatile("s_waitcnt vmcnt(0)" ::: "memory");
    }
    __builtin_amdgcn_s_barrier();
  }

  // epilogue: 32x32 C/D map (m74/m101): col=lane&31, row=(reg&3)+8*(reg>>2)+4*lhi
  const int m_base = R0 + wm * 128;
  const int n_base = C0 + wn * 64 + l31;
#pragma unroll
  for (int nj = 0; nj < 2; ++nj) {
    const int n = n_base + nj * 32;
    const float bv = bias[n];
#pragma unroll
    for (int mi = 0; mi < 4; ++mi) {
#pragma unroll
      for (int reg = 0; reg < 16; ++reg) {
        const int row = (reg & 3) + 8 * (reg >> 2) + 4 * lhi;
        const int m = m_base + mi * 32 + row;
        float v = acc[mi][nj][reg] + bv;
        if (EPI == 0) {
          v = fmaxf(v, 0.0f);
          ((unsigned short*)outp)[(size_t)m * N + n] = f2bf(v);
        } else {
          ((float*)outp)[(size_t)m * N + n] = v;
        }
      }
    }
  }
}

// ---------------- finalize (in-place on res==out): clip, affine, +x, row-normalize ----------------
__global__ __launch_bounds__(256) void k_finalize(
    float* __restrict__ res, const float* __restrict__ x,
    const float* __restrict__ out_mean, const float* __restrict__ out_std,
    const float* __restrict__ in_mean, const int* __restrict__ nmp) {
  const int wave = threadIdx.x >> 6, lane = threadIdx.x & 63;
  const size_t row = (size_t)blockIdx.x * 4 + wave;
  const float nm = (float)(*nmp);
  const size_t base = row * DOUT + (size_t)lane * 8;
  const int c = lane * 8;
  const float4 r0 = *(const float4*)(res + base);
  const float4 r1 = *(const float4*)(res + base + 4);
  float ss = r0.x * r0.x + r0.y * r0.y + r0.z * r0.z + r0.w * r0.w +
             r1.x * r1.x + r1.y * r1.y + r1.z * r1.z + r1.w * r1.w;
#pragma unroll
  for (int o = 32; o > 0; o >>= 1) ss += __shfl_xor(ss, o);
  const float rn = sqrtf(ss);
  const float sc = (rn > nm) ? (nm / rn) : 1.0f;
  const float4 os0 = *(const float4*)(out_std + c);
  const float4 os1 = *(const float4*)(out_std + c + 4);
  const float4 om0 = *(const float4*)(out_mean + c);
  const float4 om1 = *(const float4*)(out_mean + c + 4);
  const float4 im0 = *(const float4*)(in_mean + c);
  const float4 im1 = *(const float4*)(in_mean + c + 4);
  const float4 x0 = *(const float4*)(x + base);
  const float4 x1 = *(const float4*)(x + base + 4);
  float4 m0, m1;
  m0.x = r0.x * sc * os0.x + om0.x - im0.x + x0.x;
  m0.y = r0.y * sc * os0.y + om0.y - im0.y + x0.y;
  m0.z = r0.z * sc * os0.z + om0.z - im0.z + x0.z;
  m0.w = r0.w * sc * os0.w + om0.w - im0.w + x0.w;
  m1.x = r1.x * sc * os1.x + om1.x - im1.x + x1.x;
  m1.y = r1.y * sc * os1.y + om1.y - im1.y + x1.y;
  m1.z = r1.z * sc * os1.z + om1.z - im1.z + x1.z;
  m1.w = r1.w * sc * os1.w + om1.w - im1.w + x1.w;
  float s2 = m0.x * m0.x + m0.y * m0.y + m0.z * m0.z + m0.w * m0.w +
             m1.x * m1.x + m1.y * m1.y + m1.z * m1.z + m1.w * m1.w;
#pragma unroll
  for (int o = 32; o > 0; o >>= 1) s2 += __shfl_xor(s2, o);
  const float inv = 1.0f / fmaxf(sqrtf(s2), 1e-12f);
  float4 o0, o1;
  o0.x = m0.x * inv; o0.y = m0.y * inv; o0.z = m0.z * inv; o0.w = m0.w * inv;
  o1.x = m1.x * inv; o1.y = m1.y * inv; o1.z = m1.z * inv; o1.w = m1.w * inv;
  *(float4*)(res + base) = o0;
  *(float4*)(res + base + 4) = o1;
}

extern "C" void kernel_launch(void* const* d_in, const int* in_sizes, int n_in,
                              void* d_out, int out_size, void* d_ws, size_t ws_size,
                              hipStream_t stream) {
  const float* x = (const float*)d_in[0];
  const float* in_mean = (const float*)d_in[1];
  const float* in_std = (const float*)d_in[2];
  const float* out_mean = (const float*)d_in[3];
  const float* out_std = (const float*)d_in[4];
  const float* W1 = (const float*)d_in[5];
  const float* b1 = (const float*)d_in[6];
  const float* W2 = (const float*)d_in[7];
  const float* b2 = (const float*)d_in[8];
  const int* nmp = (const int*)d_in[9];
  float* out = (float*)d_out;

  // ---- workspace layout (adaptive: h holds only `chunk` batch rows) ----
  char* ws = (char*)d_ws;
  unsigned short* xn = (unsigned short*)ws;   ws += (size_t)NB * DIN * 2;    // 32 MB
  unsigned short* W1b = (unsigned short*)ws;  ws += (size_t)DHID * DIN * 2;  //  4 MB
  unsigned short* W2b = (unsigned short*)ws;  ws += (size_t)DOUT * DHID * 2; //  4 MB
  unsigned short* h = (unsigned short*)ws;    // chunk * DHID bf16

  const size_t fixedB = (size_t)(ws - (char*)d_ws);
  const size_t avail = (ws_size > fixedB) ? (ws_size - fixedB) : 0;
  long long crows = (long long)(avail / ((size_t)DHID * 2));
  if (crows > NB) crows = NB;
  crows &= ~255LL;                 // multiple of 256 (BM)
  if (crows < 256) crows = 256;
  const int chunk = (int)crows;

  // 1) xn = bf16((x - in_mean)/in_std)
  k_prep_x<<<16384, 256, 0, stream>>>((const float4*)x, in_mean, in_std,
                                      (ushort4*)xn);
  // 2) W1, W2 -> bf16
  k_cvt<<<2048, 256, 0, stream>>>((const float4*)W1, (ushort4*)W1b);
  k_cvt<<<2048, 256, 0, stream>>>((const float4*)W2, (ushort4*)W2b);

  // 3) per-chunk: h = relu(xn@W1^T + b1); res(=d_out) = h@W2^T + b2
  for (int s = 0; s < NB; s += chunk) {
    const int mc = (NB - s < chunk) ? (NB - s) : chunk;
    const int g1 = (mc / 256) * (DHID / 256);
    k_gemm<0><<<g1, 512, 0, stream>>>(xn + (size_t)s * DIN, W1b, b1, (void*)h,
                                      DHID, DIN, DHID / 256);
    const int g2 = (mc / 256) * (DOUT / 256);
    k_gemm<1><<<g2, 512, 0, stream>>>(h, W2b, b2, (void*)(out + (size_t)s * DOUT),
                                      DOUT, DHID, DOUT / 256);
  }

  // 4) finalize in-place on d_out
  k_finalize<<<NB / 4, 256, 0, stream>>>(out, x, out_mean, out_std, in_mean, nmp);
}